// Round 1
// baseline (235.966 us; speedup 1.0000x reference)
//
#include <hip/hip_runtime.h>

// CrossCompressUnit: fp32 in / fp32 out (verified R3: passed, absmax 1.6e-2).
// B=262144 rows, D=64. 16 lanes/row, float4 chunk per lane per tensor.
// R4: 2 chunks/thread (ILP-2 independent HBM streams), nontemporal
// loads/stores for the streaming tensors, weight loads amortized 2x.
// R5: replace __shfl_xor butterfly (32x ds_bpermute, LDS pipe + 4-level
// lgkmcnt chain) with pure-VALU DPP reduction: row_mirror(^15),
// row_half_mirror(^7), quad_perm(^2), quad_perm(^1). XOR masks {15,7,2,1}
// span 4 bits -> all 16 lanes end with the full row sum. No LDS pipe use.
// Floor: 256 MiB @ ~6.7 TB/s (device-achieved, per harness fills) ~= 40 us.

using f32x4 = __attribute__((ext_vector_type(4))) float;

constexpr int D_DIM = 64;
constexpr int B_ROWS = 262144;
constexpr int LANES_PER_ROW = 16;                       // 16 lanes x 4 elems = 64
constexpr int CHUNKS = B_ROWS * LANES_PER_ROW;          // float4 chunks per tensor
constexpr int PER_THREAD = 2;
constexpr int NTHREADS = CHUNKS / PER_THREAD;           // 2,097,152
constexpr int BLOCK = 256;

__device__ __forceinline__ float dot4(const f32x4 a, const f32x4 b) {
    return a[0]*b[0] + a[1]*b[1] + a[2]*b[2] + a[3]*b[3];
}

// x += DPP-permuted(x); CTRL is a compile-time DPP control code.
template<int CTRL>
__device__ __forceinline__ float dpp_add(float x) {
    int p = __builtin_amdgcn_update_dpp(0, __builtin_bit_cast(int, x),
                                        CTRL, 0xF, 0xF, true);
    return x + __builtin_bit_cast(float, p);
}

// Sum across each aligned 16-lane group; result broadcast to all 16 lanes.
// Each level is an XOR-mask involution done as a VALU DPP add:
//   0x140 row_mirror      = lane ^ 15
//   0x141 row_half_mirror = lane ^ 7
//   0x4E  quad_perm(2,3,0,1) = lane ^ 2
//   0xB1  quad_perm(1,0,3,2) = lane ^ 1
// masks {15,7,2,1} are linearly independent over GF(2) -> full 16-lane sum.
__device__ __forceinline__ float row16_sum(float x) {
    x = dpp_add<0x140>(x);
    x = dpp_add<0x141>(x);
    x = dpp_add<0x4E>(x);
    x = dpp_add<0xB1>(x);
    return x;
}

__global__ __launch_bounds__(BLOCK) void ccu_kernel(
    const f32x4* __restrict__ v,       // B*D fp32 as B*16 f32x4
    const f32x4* __restrict__ e,
    const f32x4* __restrict__ w_vv,    // D fp32 as 16 f32x4
    const f32x4* __restrict__ w_ev,
    const f32x4* __restrict__ w_ve,
    const f32x4* __restrict__ w_ee,
    const f32x4* __restrict__ bias_v,
    const f32x4* __restrict__ bias_e,
    f32x4* __restrict__ out_v,
    f32x4* __restrict__ out_e)
{
    const int tid = blockIdx.x * BLOCK + threadIdx.x;
    const int sub = tid & (LANES_PER_ROW - 1);   // chunk index within the row
    const int g0  = tid;                         // stream 0 chunk
    const int g1  = tid + NTHREADS;              // stream 1 chunk (NTHREADS%16==0
                                                 //  -> same sub, same weights)

    // two independent streaming load pairs (nontemporal: zero reuse)
    const f32x4 v0 = __builtin_nontemporal_load(&v[g0]);
    const f32x4 e0 = __builtin_nontemporal_load(&e[g0]);
    const f32x4 v1 = __builtin_nontemporal_load(&v[g1]);
    const f32x4 e1 = __builtin_nontemporal_load(&e[g1]);

    // weights + biases: 256B each, cached, amortized over both streams
    const f32x4 wvv = w_vv[sub];
    const f32x4 wev = w_ev[sub];
    const f32x4 wve = w_ve[sub];
    const f32x4 wee = w_ee[sub];
    const f32x4 bv  = bias_v[sub];
    const f32x4 be  = bias_e[sub];

    // per-lane partial dots, both rows
    float s0_vv = dot4(e0, wvv), s0_ev = dot4(v0, wev);
    float s0_ve = dot4(e0, wve), s0_ee = dot4(v0, wee);
    float s1_vv = dot4(e1, wvv), s1_ev = dot4(v1, wev);
    float s1_ve = dot4(e1, wve), s1_ee = dot4(v1, wee);

    // 16-lane row reduction, pure VALU (8 independent 4-level DPP chains)
    s0_vv = row16_sum(s0_vv);
    s0_ev = row16_sum(s0_ev);
    s0_ve = row16_sum(s0_ve);
    s0_ee = row16_sum(s0_ee);
    s1_vv = row16_sum(s1_vv);
    s1_ev = row16_sum(s1_ev);
    s1_ve = row16_sum(s1_ve);
    s1_ee = row16_sum(s1_ee);

    // v_out = v*(e.w_vv) + e*(v.w_ev) + bias_v
    // e_out = v*(e.w_ve) + e*(v.w_ee) + bias_e
    f32x4 ov0, oe0, ov1, oe1;
#pragma unroll
    for (int j = 0; j < 4; ++j) {
        ov0[j] = fmaf(v0[j], s0_vv, fmaf(e0[j], s0_ev, bv[j]));
        oe0[j] = fmaf(v0[j], s0_ve, fmaf(e0[j], s0_ee, be[j]));
        ov1[j] = fmaf(v1[j], s1_vv, fmaf(e1[j], s1_ev, bv[j]));
        oe1[j] = fmaf(v1[j], s1_ve, fmaf(e1[j], s1_ee, be[j]));
    }

    __builtin_nontemporal_store(ov0, &out_v[g0]);
    __builtin_nontemporal_store(oe0, &out_e[g0]);
    __builtin_nontemporal_store(ov1, &out_v[g1]);
    __builtin_nontemporal_store(oe1, &out_e[g1]);
}

extern "C" void kernel_launch(void* const* d_in, const int* in_sizes, int n_in,
                              void* d_out, int out_size, void* d_ws, size_t ws_size,
                              hipStream_t stream) {
    const f32x4* v      = (const f32x4*)d_in[0];
    const f32x4* e      = (const f32x4*)d_in[1];
    const f32x4* w_vv   = (const f32x4*)d_in[2];
    const f32x4* w_ev   = (const f32x4*)d_in[3];
    const f32x4* w_ve   = (const f32x4*)d_in[4];
    const f32x4* w_ee   = (const f32x4*)d_in[5];
    const f32x4* bias_v = (const f32x4*)d_in[6];
    const f32x4* bias_e = (const f32x4*)d_in[7];

    f32x4* out_v = (f32x4*)d_out;                    // fp32 v_out
    f32x4* out_e = out_v + (size_t)CHUNKS;           // fp32 e_out

    ccu_kernel<<<NTHREADS / BLOCK, BLOCK, 0, stream>>>(
        v, e, w_vv, w_ev, w_ve, w_ee, bias_v, bias_e, out_v, out_e);
}

// Round 3
// 234.297 us; speedup vs baseline: 1.0071x; 1.0071x over previous
//
#include <hip/hip_runtime.h>

// CrossCompressUnit: fp32 in / fp32 out (verified R3: passed, absmax 1.6e-2).
// B=262144 rows, D=64. 16 lanes/row, float4 chunk per lane per tensor.
// R5: pure-VALU DPP row reduction (masks {15,7,2,1}) — measured NEUTRAL vs
//     __shfl_xor -> reduction is not on the critical path. Kept (cheaper).
// R6: persistent grid-stride structure. 2048 blocks x 256 thr, 8 chunks/thread,
//     weights/biases loaded ONCE per thread (8x amortization), unrolled loop
//     with depth-1 prefetch. R6 bench was an infra failure (container died
//     twice, no counters) — R7 is the same structure, resubmitted, with the
//     last-iteration uninitialized-prefetch blemish removed (peeled epilogue).
// Floor: 256 MiB @ ~6.7 TB/s (device-achieved, per harness fills) ~= 40 us.

using f32x4 = __attribute__((ext_vector_type(4))) float;

constexpr int D_DIM = 64;
constexpr int B_ROWS = 262144;
constexpr int LANES_PER_ROW = 16;                       // 16 lanes x 4 elems = 64
constexpr int CHUNKS = B_ROWS * LANES_PER_ROW;          // 4,194,304 f32x4/tensor
constexpr int BLOCK = 256;
constexpr int NBLOCKS = 2048;                           // 8 blocks/CU nominal
constexpr int NTHREADS = BLOCK * NBLOCKS;               // 524,288
constexpr int PER_THREAD = CHUNKS / NTHREADS;           // 8
constexpr int STRIDE = NTHREADS;                        // % 16 == 0 -> sub fixed

__device__ __forceinline__ float dot4(const f32x4 a, const f32x4 b) {
    return a[0]*b[0] + a[1]*b[1] + a[2]*b[2] + a[3]*b[3];
}

// x += DPP-permuted(x); CTRL is a compile-time DPP control code.
template<int CTRL>
__device__ __forceinline__ float dpp_add(float x) {
    int p = __builtin_amdgcn_update_dpp(0, __builtin_bit_cast(int, x),
                                        CTRL, 0xF, 0xF, true);
    return x + __builtin_bit_cast(float, p);
}

// Sum across each aligned 16-lane group; result broadcast to all 16 lanes.
//   0x140 row_mirror (^15), 0x141 row_half_mirror (^7),
//   0x4E quad_perm(2,3,0,1) (^2), 0xB1 quad_perm(1,0,3,2) (^1).
// XOR masks {15,7,2,1} span 4 bits -> every lane gets the full 16-lane sum.
__device__ __forceinline__ float row16_sum(float x) {
    x = dpp_add<0x140>(x);
    x = dpp_add<0x141>(x);
    x = dpp_add<0x4E>(x);
    x = dpp_add<0xB1>(x);
    return x;
}

__device__ __forceinline__ void ccu_body(
    const f32x4 cv, const f32x4 ce,
    const f32x4 wvv, const f32x4 wev, const f32x4 wve, const f32x4 wee,
    const f32x4 bv, const f32x4 be,
    f32x4* __restrict__ out_v, f32x4* __restrict__ out_e, const int g)
{
    // per-lane partial dots + 16-lane row reduction (pure VALU DPP)
    const float s_vv = row16_sum(dot4(ce, wvv));
    const float s_ev = row16_sum(dot4(cv, wev));
    const float s_ve = row16_sum(dot4(ce, wve));
    const float s_ee = row16_sum(dot4(cv, wee));

    // v_out = v*(e.w_vv) + e*(v.w_ev) + bias_v
    // e_out = v*(e.w_ve) + e*(v.w_ee) + bias_e
    f32x4 ov, oe;
#pragma unroll
    for (int j = 0; j < 4; ++j) {
        ov[j] = fmaf(cv[j], s_vv, fmaf(ce[j], s_ev, bv[j]));
        oe[j] = fmaf(cv[j], s_ve, fmaf(ce[j], s_ee, be[j]));
    }

    __builtin_nontemporal_store(ov, &out_v[g]);
    __builtin_nontemporal_store(oe, &out_e[g]);
}

__global__ __launch_bounds__(BLOCK) void ccu_kernel(
    const f32x4* __restrict__ v,       // B*D fp32 as B*16 f32x4
    const f32x4* __restrict__ e,
    const f32x4* __restrict__ w_vv,    // D fp32 as 16 f32x4
    const f32x4* __restrict__ w_ev,
    const f32x4* __restrict__ w_ve,
    const f32x4* __restrict__ w_ee,
    const f32x4* __restrict__ bias_v,
    const f32x4* __restrict__ bias_e,
    f32x4* __restrict__ out_v,
    f32x4* __restrict__ out_e)
{
    const int tid = blockIdx.x * BLOCK + threadIdx.x;
    const int sub = tid & (LANES_PER_ROW - 1);   // chunk index within the row

    // weights + biases: 256B each, cached; loaded once, live for all 8 chunks
    const f32x4 wvv = w_vv[sub];
    const f32x4 wev = w_ev[sub];
    const f32x4 wve = w_ve[sub];
    const f32x4 wee = w_ee[sub];
    const f32x4 bv  = bias_v[sub];
    const f32x4 be  = bias_e[sub];

    // prime the pipeline: chunk 0 in flight
    f32x4 cv = __builtin_nontemporal_load(&v[tid]);
    f32x4 ce = __builtin_nontemporal_load(&e[tid]);

#pragma unroll
    for (int i = 0; i < PER_THREAD - 1; ++i) {
        const int g = tid + i * STRIDE;

        // depth-1 prefetch: issue next chunk's loads before this chunk's
        // compute+store, keeping stream loads continuously in flight
        const f32x4 nv = __builtin_nontemporal_load(&v[g + STRIDE]);
        const f32x4 ne = __builtin_nontemporal_load(&e[g + STRIDE]);

        ccu_body(cv, ce, wvv, wev, wve, wee, bv, be, out_v, out_e, g);

        cv = nv;
        ce = ne;
    }

    // peeled epilogue: last chunk, no prefetch
    ccu_body(cv, ce, wvv, wev, wve, wee, bv, be, out_v, out_e,
             tid + (PER_THREAD - 1) * STRIDE);
}

extern "C" void kernel_launch(void* const* d_in, const int* in_sizes, int n_in,
                              void* d_out, int out_size, void* d_ws, size_t ws_size,
                              hipStream_t stream) {
    const f32x4* v      = (const f32x4*)d_in[0];
    const f32x4* e      = (const f32x4*)d_in[1];
    const f32x4* w_vv   = (const f32x4*)d_in[2];
    const f32x4* w_ev   = (const f32x4*)d_in[3];
    const f32x4* w_ve   = (const f32x4*)d_in[4];
    const f32x4* w_ee   = (const f32x4*)d_in[5];
    const f32x4* bias_v = (const f32x4*)d_in[6];
    const f32x4* bias_e = (const f32x4*)d_in[7];

    f32x4* out_v = (f32x4*)d_out;                    // fp32 v_out
    f32x4* out_e = out_v + (size_t)CHUNKS;           // fp32 e_out

    ccu_kernel<<<NBLOCKS, BLOCK, 0, stream>>>(
        v, e, w_vv, w_ev, w_ve, w_ee, bias_v, bias_e, out_v, out_e);
}